// Round 4
// baseline (1010.375 us; speedup 1.0000x reference)
//
#include <hip/hip_runtime.h>
#include <hip/hip_bf16.h>
#include <math.h>

typedef __hip_bfloat16 bf16;
typedef unsigned short u16;
typedef __attribute__((ext_vector_type(8))) short short8;
typedef __attribute__((ext_vector_type(4))) float f32x4;
typedef __attribute__((ext_vector_type(4))) unsigned u32x4;

#define PP 1024
#define LL 32
#define EE 512
#define DD 768
#define NLAYER 6
#define FFDIM 3072

__device__ __forceinline__ float bf2f(u16 u) { return __uint_as_float(((unsigned)u) << 16); }
// fp32 -> bf16 (RNE), finite inputs only
__device__ __forceinline__ u16 f2b(float x) {
  unsigned u = __float_as_uint(x);
  return (u16)((u + 0x7FFFu + ((u >> 16) & 1u)) >> 16);
}

// ---------------------------------------------------------------------------
// 4-region fp32 -> bf16 bulk convert. Region picked by blockIdx.y; counts in
// float4 units. Unused regions: n=0. One pass per layer: weight bf16 copies
// are then read (L2/L3-resident) by all 16 m-tiles of each GEMM -- cheaper
// than fusing the convert into B-staging (r2 post-mortem: fused = 16x
// redundant VALU + 2x fetch bytes, +~100us).
// ---------------------------------------------------------------------------
__global__ __launch_bounds__(256) void cvt4(
    const float* s0, const float* s1, const float* s2, const float* s3,
    u16* d0, u16* d1, u16* d2, u16* d3,
    int n0, int n1, int n2, int n3)
{
  int r = blockIdx.y;
  const float* s = r == 0 ? s0 : r == 1 ? s1 : r == 2 ? s2 : s3;
  u16* d        = r == 0 ? d0 : r == 1 ? d1 : r == 2 ? d2 : d3;
  int n4        = r == 0 ? n0 : r == 1 ? n1 : r == 2 ? n2 : n3;
  int i = blockIdx.x * 256 + threadIdx.x;
  if (i < n4) {
    float4 v = ((const float4*)s)[i];
    ushort4 o;
    o.x = f2b(v.x); o.y = f2b(v.y); o.z = f2b(v.z); o.w = f2b(v.w);
    ((ushort4*)d)[i] = o;
  }
}

// ---------------------------------------------------------------------------
// emb_table[r][k] = byte_emb[r>>5][k] + local_pos[r&31][k], bf16 out.
// [8192, 512]: one row per (token value, local position) pair.
// ---------------------------------------------------------------------------
__global__ __launch_bounds__(256) void embed_table(
    const float* __restrict__ be, const float* __restrict__ lp, bf16* __restrict__ T)
{
  int i = blockIdx.x * 256 + threadIdx.x;   // 8192 * 64 threads, 8 elems each
  int r = i >> 6, c = (i & 63) << 3;
  int t = r >> 5, l = r & 31;
  const float* bp = be + ((long)t << 9) + c;
  const float* pp = lp + ((long)l << 9) + c;
  float4 x0 = *(const float4*)bp, x1 = *(const float4*)(bp + 4);
  float4 y0 = *(const float4*)pp, y1 = *(const float4*)(pp + 4);
  short8 o;
  o[0] = (short)f2b(x0.x + y0.x); o[1] = (short)f2b(x0.y + y0.y);
  o[2] = (short)f2b(x0.z + y0.z); o[3] = (short)f2b(x0.w + y0.w);
  o[4] = (short)f2b(x1.x + y1.x); o[5] = (short)f2b(x1.y + y1.y);
  o[6] = (short)f2b(x1.z + y1.z); o[7] = (short)f2b(x1.w + y1.w);
  *(short8*)((u16*)T + ((long)r << 9) + c) = o;
}

// ---------------------------------------------------------------------------
// C = A @ B^T (+bias)(+addf)(gelu). A bf16 [M,K], B bf16 [N,K], fp32 accum.
// 64x64 tile / 256 threads, BK=64, double-buffered LDS, one barrier per
// chunk, next chunk's global loads issued before this chunk's MFMAs.
// blockIdx.x = m-tile (fastest): weight n-tiles stay L2-resident.
// act: 0 = none, 1 = gelu, 2 = split-K partial write (bias applied only for
// bz==0; Cf = partial pool, partial z at element offset bz*sCb; no atomics --
// the following ln_kernel sums the partials).
// Split-K / batching via blockIdx.z: sAb/sBb are element offsets (K-offset
// for split-K, batch stride otherwise); sCb is the C z/batch offset.
// M % 64 == 0; N, K guarded (K tail of 32).
// ---------------------------------------------------------------------------
__global__ __launch_bounds__(256) void gemm64(
    const bf16* A, long sAb, int lda,
    const bf16* B, long sBb, int ldb,
    float* Cf, bf16* Cb, long sCb, int ldc,
    const float* bias, int biasStride,
    const float* addf,
    int M, int N, int K, int act)
{
  __shared__ u16 As[2][64][72];   // stride 144 B: 16B-aligned, 2-way-only banks
  __shared__ u16 Bs[2][64][72];
  const int bz = blockIdx.z;
  const u16* Ap = (const u16*)A + (long)bz * sAb;
  const u16* Bp = (const u16*)B + (long)bz * sBb;
  const long coff = (long)bz * sCb;
  const int m0 = blockIdx.x << 6, n0 = blockIdx.y << 6;
  const int tid = threadIdx.x;
  const int wave = tid >> 6, lane = tid & 63;
  const int sr = tid >> 3;          // staging row 0..31 (and +32)
  const int scc = (tid & 7) << 3;   // staging col 0..56
  const int br0 = n0 + sr, br1 = n0 + sr + 32;
  const short8 zz = {0,0,0,0,0,0,0,0};
  f32x4 acc[4] = {{0.f,0.f,0.f,0.f},{0.f,0.f,0.f,0.f},{0.f,0.f,0.f,0.f},{0.f,0.f,0.f,0.f}};

  // prologue: stage chunk 0 into buffer 0
  {
    int ch = K < 64 ? K : 64;
    bool kv = scc < ch;
    short8 a0 = zz, a1 = zz, b0 = zz, b1 = zz;
    if (kv) {
      a0 = *(const short8*)(Ap + (long)(m0 + sr) * lda + scc);
      a1 = *(const short8*)(Ap + (long)(m0 + sr + 32) * lda + scc);
      if (br0 < N) b0 = *(const short8*)(Bp + (long)br0 * ldb + scc);
      if (br1 < N) b1 = *(const short8*)(Bp + (long)br1 * ldb + scc);
    }
    *(short8*)&As[0][sr][scc] = a0;
    *(short8*)&As[0][sr + 32][scc] = a1;
    *(short8*)&Bs[0][sr][scc] = b0;
    *(short8*)&Bs[0][sr + 32][scc] = b1;
  }
  __syncthreads();

  const int arow = (wave << 4) + (lane & 15);
  const int kq = (lane >> 4) << 3;
  int buf = 0;
  for (int k0 = 0; k0 < K; k0 += 64) {
    int knext = k0 + 64;
    bool more = knext < K;
    short8 a0 = zz, a1 = zz, b0 = zz, b1 = zz;
    if (more) {   // issue next chunk's loads before MFMAs (overlap)
      int ch = K - knext; if (ch > 64) ch = 64;
      bool kv = scc < ch;
      if (kv) {
        a0 = *(const short8*)(Ap + (long)(m0 + sr) * lda + knext + scc);
        a1 = *(const short8*)(Ap + (long)(m0 + sr + 32) * lda + knext + scc);
        if (br0 < N) b0 = *(const short8*)(Bp + (long)br0 * ldb + knext + scc);
        if (br1 < N) b1 = *(const short8*)(Bp + (long)br1 * ldb + knext + scc);
      }
    }
    int rem = K - k0; if (rem > 64) rem = 64;
    {
      short8 af = *(const short8*)&As[buf][arow][kq];
#pragma unroll
      for (int nt = 0; nt < 4; nt++) {
        short8 bfr = *(const short8*)&Bs[buf][(nt << 4) + (lane & 15)][kq];
        acc[nt] = __builtin_amdgcn_mfma_f32_16x16x32_bf16(af, bfr, acc[nt], 0, 0, 0);
      }
    }
    if (rem > 32) {
      short8 af = *(const short8*)&As[buf][arow][32 + kq];
#pragma unroll
      for (int nt = 0; nt < 4; nt++) {
        short8 bfr = *(const short8*)&Bs[buf][(nt << 4) + (lane & 15)][32 + kq];
        acc[nt] = __builtin_amdgcn_mfma_f32_16x16x32_bf16(af, bfr, acc[nt], 0, 0, 0);
      }
    }
    if (more) {
      int nb = buf ^ 1;
      *(short8*)&As[nb][sr][scc] = a0;
      *(short8*)&As[nb][sr + 32][scc] = a1;
      *(short8*)&Bs[nb][sr][scc] = b0;
      *(short8*)&Bs[nb][sr + 32][scc] = b1;
      __syncthreads();
      buf = nb;
    }
  }

  int rbase = m0 + (wave << 4) + ((lane >> 4) << 2);
#pragma unroll
  for (int nt = 0; nt < 4; nt++) {
    int c = n0 + (nt << 4) + (lane & 15);
    if (c >= N) continue;
    float bvl = bias ? bias[bz * biasStride + c] : 0.f;
    if (act == 2 && bz != 0) bvl = 0.f;
#pragma unroll
    for (int j = 0; j < 4; j++) {
      int r = rbase + j;
      long idx = coff + (long)r * ldc + c;
      float v = acc[nt][j] + bvl;
      if (addf) v += addf[idx];
      if (act == 1) v = 0.5f * v * (1.f + erff(v * 0.70710678118654752f));
      if (Cf) Cf[idx] = v;
      if (Cb) Cb[idx] = __float2bfloat16(v);
    }
  }
}

// ---------------------------------------------------------------------------
// Fused flash-style MHA for phase 2: per (q-tile of 32, head) block, 2 waves,
// each wave owns 16 q-rows and streams all 1024 keys in 32-key tiles.
// Swapped QK^T: mfma(K_frag, Q_frag) -> C[col=q-row(lane&15)][row=key
// ((lane>>4)*4+r)] so each lane holds 8 scores of ONE q-row; row max/sum are
// 2x shfl_xor. Online softmax (exact-skip rescale when max doesn't grow).
// P repack to PV A-frag (key groups of 4 -> 8) via 8 __shfl (explicit
// cross-lane -- no LDS ordering hazards). PV: B operand read from Vt[d][k]
// directly. Scores never touch memory and are not bf16-rounded; P is
// bf16-rounded as in the unfused path.
// ---------------------------------------------------------------------------
__global__ __launch_bounds__(128) void fused_attn(
    const bf16* __restrict__ qkvt,  // [1024,2304]  Q|K|V
    const bf16* __restrict__ Vt,    // [768,1024]   V transposed (d-major)
    bf16* __restrict__ attn)        // [1024,768]
{
  const int h = blockIdx.y;
  const int wid = threadIdx.x >> 6;
  const int lane = threadIdx.x & 63;
  const int q0 = (blockIdx.x << 5) + (wid << 4);
  const int lr = lane & 15;
  const int lq = lane >> 4;
  const float scale = 0.10206207261596577f;  // 96^-0.5

  const u16* qp = (const u16*)qkvt;
  const u16* kp = qp + 768 + h * 96 + (lq << 3);
  const u16* vp = (const u16*)Vt + ((long)(h * 96 + lr) << 10) + (lq << 3);

  // Q fragments (B operand of swapped QK): Q[q0+lr][h*96 + c*32 + lq*8 ..+7]
  short8 qf[3];
#pragma unroll
  for (int c = 0; c < 3; c++)
    qf[c] = *(const short8*)(qp + (long)(q0 + lr) * 2304 + h * 96 + (c << 5) + (lq << 3));

  f32x4 o[6] = {{0.f,0.f,0.f,0.f},{0.f,0.f,0.f,0.f},{0.f,0.f,0.f,0.f},
                {0.f,0.f,0.f,0.f},{0.f,0.f,0.f,0.f},{0.f,0.f,0.f,0.f}};
  float m = -INFINITY, l = 0.f;

  for (int k0 = 0; k0 < 1024; k0 += 32) {
    f32x4 s0 = {0.f,0.f,0.f,0.f}, s1 = {0.f,0.f,0.f,0.f};
#pragma unroll
    for (int c = 0; c < 3; c++) {
      short8 kf0 = *(const short8*)(kp + (long)(k0 + lr) * 2304 + (c << 5));
      short8 kf1 = *(const short8*)(kp + (long)(k0 + 16 + lr) * 2304 + (c << 5));
      s0 = __builtin_amdgcn_mfma_f32_16x16x32_bf16(kf0, qf[c], s0, 0, 0, 0);
      s1 = __builtin_amdgcn_mfma_f32_16x16x32_bf16(kf1, qf[c], s1, 0, 0, 0);
    }
    // lane holds scores of q-row lr at keys k0+lq*4+r (s0) and k0+16+lq*4+r (s1)
    float e0[4], e1[4];
    float mx = -INFINITY;
#pragma unroll
    for (int r = 0; r < 4; r++) {
      e0[r] = s0[r] * scale;
      e1[r] = s1[r] * scale;
      mx = fmaxf(mx, fmaxf(e0[r], e1[r]));
    }
    mx = fmaxf(mx, __shfl_xor(mx, 16));
    mx = fmaxf(mx, __shfl_xor(mx, 32));
    float mn = fmaxf(m, mx);
    float ts = 0.f;
#pragma unroll
    for (int r = 0; r < 4; r++) {
      e0[r] = __expf(e0[r] - mn);
      e1[r] = __expf(e1[r] - mn);
      ts += e0[r] + e1[r];
    }
    ts += __shfl_xor(ts, 16);
    ts += __shfl_xor(ts, 32);
    if (!__all(mx <= m)) {   // some q-row's max grew: rescale O (exact skip else)
      float f = __expf(m - mn);
      float fr[4];
#pragma unroll
      for (int r = 0; r < 4; r++) fr[r] = __shfl(f, (lq << 2) + r);
#pragma unroll
      for (int n = 0; n < 6; n++)
#pragma unroll
        for (int r = 0; r < 4; r++) o[n][r] *= fr[r];
      l *= f;
    }
    l += ts;
    m = mn;

    // pack P to bf16 pairs, then cross-lane repack: PV A-frag lane (lq,lr)
    // needs keys 8*lq..8*lq+7 of q-row lr; sources are quadrant pair
    // (2*(lq&1), 2*(lq&1)+1), kt = lq>>1.
    unsigned a01 = ((unsigned)f2b(e0[1]) << 16) | f2b(e0[0]);
    unsigned a23 = ((unsigned)f2b(e0[3]) << 16) | f2b(e0[2]);
    unsigned b01 = ((unsigned)f2b(e1[1]) << 16) | f2b(e1[0]);
    unsigned b23 = ((unsigned)f2b(e1[3]) << 16) | f2b(e1[2]);
    int sA = lr + ((lq & 1) << 5);   // lane with lower 4 target keys
    int sB = sA + 16;                // lane with upper 4 target keys
    unsigned qa01 = (unsigned)__shfl((int)a01, sA);
    unsigned qa23 = (unsigned)__shfl((int)a23, sA);
    unsigned qb01 = (unsigned)__shfl((int)b01, sA);
    unsigned qb23 = (unsigned)__shfl((int)b23, sA);
    unsigned ra01 = (unsigned)__shfl((int)a01, sB);
    unsigned ra23 = (unsigned)__shfl((int)a23, sB);
    unsigned rb01 = (unsigned)__shfl((int)b01, sB);
    unsigned rb23 = (unsigned)__shfl((int)b23, sB);
    bool hi = lq >= 2;               // kt1 keys for quadrants 2,3
    u32x4 wv;
    wv[0] = hi ? qb01 : qa01;
    wv[1] = hi ? qb23 : qa23;
    wv[2] = hi ? rb01 : ra01;
    wv[3] = hi ? rb23 : ra23;
    short8 pa = __builtin_bit_cast(short8, wv);

#pragma unroll
    for (int n = 0; n < 6; n++) {
      short8 vf = *(const short8*)(vp + (long)(n << 4) * 1024 + k0);
      o[n] = __builtin_amdgcn_mfma_f32_16x16x32_bf16(pa, vf, o[n], 0, 0, 0);
    }
  }

  float inv = 1.f / l;
  float ir[4];
#pragma unroll
  for (int r = 0; r < 4; r++) ir[r] = __shfl(inv, (lq << 2) + r);
  u16* op = (u16*)attn + (long)(q0 + (lq << 2)) * 768 + h * 96 + lr;
#pragma unroll
  for (int r = 0; r < 4; r++)
#pragma unroll
    for (int n = 0; n < 6; n++)
      op[(long)r * 768 + (n << 4)] = f2b(o[n][r] * ir[r]);
}

// ---------------------------------------------------------------------------
// Per-patch MHA over 32 bytes (4 heads, d=128) fused with masked mean.
// Q/K come from the per-(token,pos) table qkt [8192,1024]: row for byte j of
// patch p is (tokens[p*32+j]<<5)|j. MFMA QK^T (no LDS, no spills): wave =
// head; 2x2 16x16 C-tiles, 4 k-chunks.
// Softmax + column-mean via shuffle reductions in MFMA C-layout
// (row = (lane>>4)*4 + reg + ti*16, col = (lane&15) + tj*16).
// V path commuted: z_h = wsum_h @ emb (emb recomputed from fp32 tables).
// ---------------------------------------------------------------------------
__global__ __launch_bounds__(256) void patch_attn(
    const bf16* __restrict__ qkt,  // [8192, 1024] = [Q|K] per (token,pos)
    const int* __restrict__ tokens, const int* __restrict__ lengths,
    const float* __restrict__ byte_emb, const float* __restrict__ local_pos,
    bf16* __restrict__ Z)          // [1024, 4, 512]
{
  __shared__ float wsum[4][32];
  __shared__ int tok_s[32];
  __shared__ int cnt_s;
  int p = blockIdx.x;
  int tid = threadIdx.x;
  if (tid < 32) tok_s[tid] = tokens[p * 32 + tid];
  if (tid == 0) cnt_s = lengths[p];
  __syncthreads();
  int cnt = cnt_s;
  int h = tid >> 6, lane = tid & 63;
  const int rsel = lane & 15;
  const int ksel = (lane >> 4) << 3;
  const u16* qkb = (const u16*)qkt + h * 128;
  const long r0 = ((long)((tok_s[rsel] << 5) | rsel)) << 10;
  const long r1 = ((long)((tok_s[16 + rsel] << 5) | (16 + rsel))) << 10;

  f32x4 acc[2][2] = {{{0.f,0.f,0.f,0.f},{0.f,0.f,0.f,0.f}},
                     {{0.f,0.f,0.f,0.f},{0.f,0.f,0.f,0.f}}};
#pragma unroll
  for (int kc = 0; kc < 4; kc++) {
    int ko = kc * 32 + ksel;
    short8 a0 = *(const short8*)(qkb + r0 + ko);
    short8 a1 = *(const short8*)(qkb + r1 + ko);
    short8 b0 = *(const short8*)(qkb + r0 + 512 + ko);
    short8 b1 = *(const short8*)(qkb + r1 + 512 + ko);
    acc[0][0] = __builtin_amdgcn_mfma_f32_16x16x32_bf16(a0, b0, acc[0][0], 0, 0, 0);
    acc[0][1] = __builtin_amdgcn_mfma_f32_16x16x32_bf16(a0, b1, acc[0][1], 0, 0, 0);
    acc[1][0] = __builtin_amdgcn_mfma_f32_16x16x32_bf16(a1, b0, acc[1][0], 0, 0, 0);
    acc[1][1] = __builtin_amdgcn_mfma_f32_16x16x32_bf16(a1, b1, acc[1][1], 0, 0, 0);
  }

  const float scale = 0.088388347648318447f;  // 128^-0.5
  int j0 = lane & 15, j1 = 16 + j0;
  bool v0 = j0 < cnt, v1 = j1 < cnt;
  int rowq = (lane >> 4) << 2;
  float cs0 = 0.f, cs1 = 0.f;   // column-sum partials for cols j0, j1
#pragma unroll
  for (int ti = 0; ti < 2; ti++) {
    float s0[4], s1[4], mx[4], sm[4], e0[4], e1[4];
#pragma unroll
    for (int r = 0; r < 4; r++) {
      s0[r] = acc[ti][0][r] * scale;
      s1[r] = acc[ti][1][r] * scale;
      float a = v0 ? s0[r] : -1e30f;
      float b = v1 ? s1[r] : -1e30f;
      mx[r] = fmaxf(a, b);
    }
#pragma unroll
    for (int d = 1; d < 16; d <<= 1)
#pragma unroll
      for (int r = 0; r < 4; r++) mx[r] = fmaxf(mx[r], __shfl_xor(mx[r], d));
#pragma unroll
    for (int r = 0; r < 4; r++) {
      e0[r] = v0 ? __expf(s0[r] - mx[r]) : 0.f;
      e1[r] = v1 ? __expf(s1[r] - mx[r]) : 0.f;
      sm[r] = e0[r] + e1[r];
    }
#pragma unroll
    for (int d = 1; d < 16; d <<= 1)
#pragma unroll
      for (int r = 0; r < 4; r++) sm[r] += __shfl_xor(sm[r], d);
#pragma unroll
    for (int r = 0; r < 4; r++) {
      int row = ti * 16 + rowq + r;
      if (row < cnt) {
        float inv = 1.f / sm[r];
        cs0 += e0[r] * inv;
        cs1 += e1[r] * inv;
      }
    }
  }
  cs0 += __shfl_xor(cs0, 16); cs0 += __shfl_xor(cs0, 32);
  cs1 += __shfl_xor(cs1, 16); cs1 += __shfl_xor(cs1, 32);
  if (lane < 16) {
    float invc = 1.f / (float)cnt;
    wsum[h][lane] = cs0 * invc;
    wsum[h][16 + lane] = cs1 * invc;
  }
  __syncthreads();

  // z_h[e] = sum_j wsum[h][j] * emb[j][e]
  for (int e = tid; e < 512; e += 256) {
    float za0 = 0.f, za1 = 0.f, za2 = 0.f, za3 = 0.f;
    for (int j = 0; j < cnt; j++) {
      float ev = byte_emb[((long)tok_s[j] << 9) + e] + local_pos[((long)j << 9) + e];
      za0 += wsum[0][j] * ev;
      za1 += wsum[1][j] * ev;
      za2 += wsum[2][j] * ev;
      za3 += wsum[3][j] * ev;
    }
    long zb = (long)p * 2048;
    Z[zb + e]        = __float2bfloat16(za0);
    Z[zb + 512 + e]  = __float2bfloat16(za1);
    Z[zb + 1024 + e] = __float2bfloat16(za2);
    Z[zb + 1536 + e] = __float2bfloat16(za3);
  }
}

// ---------------------------------------------------------------------------
// Row LayerNorm over 768 cols, with optional fused residual-partial sum:
// v = x[row] + a0 + a1 + a2 + a3 (each nullable); if hout, hout[row] = v
// (persist updated residual); then LN(v)*w+b -> outb (bf16) / outf (fp32).
// 256 threads, 3 cols/thread, register-resident (static unroll -- no scratch).
// ---------------------------------------------------------------------------
__global__ __launch_bounds__(256) void ln_kernel(
    const float* __restrict__ x,
    const float* __restrict__ a0, const float* __restrict__ a1,
    const float* __restrict__ a2, const float* __restrict__ a3,
    float* __restrict__ hout,
    const float* __restrict__ w, const float* __restrict__ b,
    bf16* outb, float* outf)
{
  __shared__ float red[8];
  __shared__ float mv[2];
  int row = blockIdx.x;
  long base = (long)row * DD;
  int tid = threadIdx.x, lane = tid & 63, wave = tid >> 6;
  float vv[3];
  float s = 0.f, s2 = 0.f;
#pragma unroll
  for (int j = 0; j < 3; j++) {
    long c = base + tid + j * 256;
    float v = x[c];
    if (a0) v += a0[c];
    if (a1) v += a1[c];
    if (a2) v += a2[c];
    if (a3) v += a3[c];
    if (hout) hout[c] = v;
    vv[j] = v; s += v; s2 += v * v;
  }
  for (int o = 32; o; o >>= 1) { s += __shfl_down(s, o); s2 += __shfl_down(s2, o); }
  if (lane == 0) { red[wave] = s; red[4 + wave] = s2; }
  __syncthreads();
  if (tid == 0) {
    float ts = red[0] + red[1] + red[2] + red[3];
    float ts2 = red[4] + red[5] + red[6] + red[7];
    float mu = ts / DD;
    float var = ts2 / DD - mu * mu;
    mv[0] = mu; mv[1] = rsqrtf(var + 1e-5f);
  }
  __syncthreads();
  float mu = mv[0], rstd = mv[1];
#pragma unroll
  for (int j = 0; j < 3; j++) {
    int c = tid + j * 256;
    float v = (vv[j] - mu) * rstd * w[c] + b[c];
    if (outb) outb[base + c] = __float2bfloat16(v);
    if (outf) outf[base + c] = v;
  }
}

// ---------------------------------------------------------------------------
// Vt[d][k] = qkv[k][1536 + d]  (V part), 32x32 LDS tiles. bf16.
// ---------------------------------------------------------------------------
__global__ __launch_bounds__(256) void transpose_v(
    const bf16* __restrict__ qkv, bf16* __restrict__ Vt)
{
  __shared__ u16 tile[32][33];
  int k0 = blockIdx.x << 5;
  int d0 = blockIdx.y << 5;
  int tx = threadIdx.x & 31, ty = threadIdx.x >> 5;
  const u16* q = (const u16*)qkv;
  for (int i = ty; i < 32; i += 8)
    tile[i][tx] = q[(long)(k0 + i) * 2304 + 1536 + d0 + tx];
  __syncthreads();
  u16* vt = (u16*)Vt;
  for (int i = ty; i < 32; i += 8)
    vt[(long)(d0 + i) * 1024 + k0 + tx] = tile[tx][i];
}

extern "C" void kernel_launch(void* const* d_in, const int* in_sizes, int n_in,
                              void* d_out, int out_size, void* d_ws, size_t ws_size,
                              hipStream_t stream)
{
  const int*   tokens    = (const int*)d_in[0];
  const int*   lengths   = (const int*)d_in[1];
  const float* byte_emb  = (const float*)d_in[2];
  const float* local_pos = (const float*)d_in[3];
  const float* patch_pos = (const float*)d_in[4];
  const float* pa_qkv_w  = (const float*)d_in[5];
  const float* pa_qkv_b  = (const float*)d_in[6];
  const float* pa_out_w  = (const float*)d_in[7];
  const float* pa_out_b  = (const float*)d_in[8];
  const float* proj_w    = (const float*)d_in[9];
  const float* proj_b    = (const float*)d_in[10];
  const float* Wqkv      = (const float*)d_in[11];
  const float* Bqkv      = (const float*)d_in[12];
  const float* Wout      = (const float*)d_in[13];
  const float* Bout      = (const float*)d_in[14];
  const float* ln1w      = (const float*)d_in[15];
  const float* ln1b      = (const float*)d_in[16];
  const float* ln2w      = (const float*)d_in[17];
  const float* ln2b      = (const float*)d_in[18];
  const float* W1        = (const float*)d_in[19];
  const float* B1        = (const float*)d_in[20];
  const float* W2        = (const float*)d_in[21];
  const float* B2        = (const float*)d_in[22];
  const float* lnfw      = (const float*)d_in[23];
  const float* lnfb      = (const float*)d_in[24];

  char* ws = (char*)d_ws;
  const size_t MB = 1ull << 20;
  // ---- layout (<= 73 MB; proven budget >= 82 MB) ----
  bf16* qkT    = (bf16*)(ws);              // [0,16)  phase1 QK table [8192,1024]
  bf16* qkvt   = (bf16*)(ws + 16 * MB);    // [16,21) [1024,2304]
  bf16* Vt     = (bf16*)(ws + 21 * MB);    // [21,23) [768,1024]
  bf16* attn   = (bf16*)(ws + 23 * MB);    // [23,25) [1024,768]
  bf16* ffb    = (bf16*)(ws + 25 * MB);    // [25,31) [1024,3072]
  float* h     = (float*)(ws + 31 * MB);   // [31,34) [1024,768] fp32
  bf16* hn     = (bf16*)(ws + 34 * MB);    // [34,36)
  u16*  Lw     = (u16*)(ws + 36 * MB);     // [36,50) per-layer bf16 weights
  bf16* embT   = (bf16*)(ws + 50 * MB);    // [50,58) phase1 emb table [8192,512]
  float* hp    = (float*)(ws + 58 * MB);   // [58,70) split-K partials 4x[1024,768] fp32 (phase2)
  bf16* Z      = (bf16*)(ws + 64 * MB);    // [64,68) [1024,4,512] (phase1 only; overlaps hp)
  bf16* o_mean = (bf16*)(ws + 68 * MB);    // [68,69) (phase1)
  bf16* t1     = (bf16*)(ws + 69 * MB);    // [69,70) (phase1)
  u16*  P1w    = (u16*)(ws + 70 * MB);     // [70,73) phase1 bf16 weights

  const long PSTRIDE = (long)PP * DD;      // partial slot stride (elements)

  // per-layer pool offsets (u16 elements)
  const long oLQKV = 0;          // [2304,768]
  const long oLOUT = 1769472;    // [768,768]
  const long oLW1  = 2359296;    // [3072,768]
  const long oLW2  = 4718592;    // [768,3072]
  // phase-1 pool offsets
  const long oPAQ  = 0;          // [1536,512]
  const long oPAO  = 786432;     // [512,512]
  const long oPRJ  = 1048576;    // [768,512]

  // ---- phase 1 ----
  cvt4<<<dim3(768, 3), 256, 0, stream>>>(
      pa_qkv_w, pa_out_w, proj_w, nullptr,
      P1w + oPAQ, P1w + oPAO, P1w + oPRJ, nullptr,
      786432 / 4, 262144 / 4, 393216 / 4, 0);
  // embT[(t<<5)|l] = byte_emb[t] + local_pos[l]  (bf16, all 8192 combos)
  embed_table<<<2048, 256, 0, stream>>>(byte_emb, local_pos, embT);
  // qkT = embT @ Wqk^T + bqk   [8192,1024]: 4x fewer FLOPs than per-byte Q/K
  gemm64<<<dim3(128, 16, 1), 256, 0, stream>>>(
      embT, 0, EE, (bf16*)(P1w + oPAQ), 0, EE, nullptr, qkT, 0, 1024,
      pa_qkv_b, 0, nullptr, 8192, 1024, EE, 0);
  patch_attn<<<PP, 256, 0, stream>>>(
      qkT, tokens, lengths, byte_emb, local_pos, Z);
  // o_mean[:, h*128:(h+1)*128] = Z[:,h,:] @ Wv_h^T + bv_h
  gemm64<<<dim3(16, 2, 4), 256, 0, stream>>>(
      Z, 512, 2048, (bf16*)(P1w + oPAQ + 1024L * EE), 128L * EE, EE,
      nullptr, o_mean, 128, EE, pa_qkv_b + 1024, 128, nullptr, PP, 128, EE, 0);
  // t1 = o_mean @ pa_out_w^T + b
  gemm64<<<dim3(16, 8, 1), 256, 0, stream>>>(
      o_mean, 0, EE, (bf16*)(P1w + oPAO), 0, EE, nullptr, t1, 0, EE,
      pa_out_b, 0, nullptr, PP, EE, EE, 0);
  // h = t1 @ proj_w^T + b + patch_pos (fp32)
  gemm64<<<dim3(16, 12, 1), 256, 0, stream>>>(
      t1, 0, EE, (bf16*)(P1w + oPRJ), 0, EE, h, nullptr, 0, DD,
      proj_b, 0, patch_pos, PP, DD, EE, 0);

  // ---- phase 2: transformer encoder ----
  for (int i = 0; i < NLAYER; i++) {
    cvt4<<<dim3(2304, 4), 256, 0, stream>>>(
        Wqkv + (long)i * 2304 * DD, Wout + (long)i * DD * DD,
        W1 + (long)i * FFDIM * DD, W2 + (long)i * DD * FFDIM,
        Lw + oLQKV, Lw + oLOUT, Lw + oLW1, Lw + oLW2,
        1769472 / 4, 589824 / 4, 2359296 / 4, 2359296 / 4);
    // ln1: for i>0 also folds in previous layer's ff2 partials and updates h
    if (i == 0)
      ln_kernel<<<PP, 256, 0, stream>>>(h, nullptr, nullptr, nullptr, nullptr,
                                        nullptr, ln1w + i * DD, ln1b + i * DD, hn, nullptr);
    else
      ln_kernel<<<PP, 256, 0, stream>>>(h, hp, hp + PSTRIDE, hp + 2 * PSTRIDE, hp + 3 * PSTRIDE,
                                        h, ln1w + i * DD, ln1b + i * DD, hn, nullptr);
    gemm64<<<dim3(16, 36, 1), 256, 0, stream>>>(
        hn, 0, DD, (bf16*)(Lw + oLQKV), 0, DD, nullptr, qkvt, 0, 2304,
        Bqkv + i * 2304, 0, nullptr, PP, 2304, DD, 0);
    transpose_v<<<dim3(32, 24), 256, 0, stream>>>(qkvt, Vt);
    // fused QK^T + softmax + PV (flash-style, no score materialization)
    fused_attn<<<dim3(32, 8), 128, 0, stream>>>(qkvt, Vt, attn);
    // out-proj split-K 2x -> partials hp[0..1] (no atomics; summed in ln2)
    gemm64<<<dim3(16, 12, 2), 256, 0, stream>>>(
        attn, 384, DD, (bf16*)(Lw + oLOUT), 384, DD, hp, nullptr, PSTRIDE, DD,
        Bout + i * DD, 0, nullptr, PP, DD, 384, 2);
    // ln2: h += p0 + p1, then LN -> hn
    ln_kernel<<<PP, 256, 0, stream>>>(h, hp, hp + PSTRIDE, nullptr, nullptr,
                                      h, ln2w + i * DD, ln2b + i * DD, hn, nullptr);
    // ffb = gelu(hn @ W1^T + b1)
    gemm64<<<dim3(16, 48, 1), 256, 0, stream>>>(
        hn, 0, DD, (bf16*)(Lw + oLW1), 0, DD, nullptr, ffb, 0, FFDIM,
        B1 + i * FFDIM, 0, nullptr, PP, FFDIM, DD, 1);
    // ff2 split-K 4x -> partials hp[0..3] (summed in next ln1 / final ln)
    gemm64<<<dim3(16, 12, 4), 256, 0, stream>>>(
        ffb, 768, FFDIM, (bf16*)(Lw + oLW2), 768, FFDIM, hp, nullptr, PSTRIDE, DD,
        B2 + i * DD, 0, nullptr, PP, DD, 768, 2);
  }
  // final LN folds in layer-5 ff2 partials
  ln_kernel<<<PP, 256, 0, stream>>>(h, hp, hp + PSTRIDE, hp + 2 * PSTRIDE, hp + 3 * PSTRIDE,
                                    nullptr, lnfw, lnfb, nullptr, (float*)d_out);
}

// Round 5
// 975.168 us; speedup vs baseline: 1.0361x; 1.0361x over previous
//
#include <hip/hip_runtime.h>
#include <hip/hip_bf16.h>
#include <math.h>

typedef __hip_bfloat16 bf16;
typedef unsigned short u16;
typedef __attribute__((ext_vector_type(8))) short short8;
typedef __attribute__((ext_vector_type(4))) float f32x4;
typedef __attribute__((ext_vector_type(4))) unsigned u32x4;

#define PP 1024
#define LL 32
#define EE 512
#define DD 768
#define NLAYER 6
#define FFDIM 3072

__device__ __forceinline__ float bf2f(u16 u) { return __uint_as_float(((unsigned)u) << 16); }
// fp32 -> bf16 (RNE), finite inputs only
__device__ __forceinline__ u16 f2b(float x) {
  unsigned u = __float_as_uint(x);
  return (u16)((u + 0x7FFFu + ((u >> 16) & 1u)) >> 16);
}

// ---------------------------------------------------------------------------
// 4-region fp32 -> bf16 bulk convert. Region picked by blockIdx.y; counts in
// float4 units. Unused regions: n=0. One pass per layer: weight bf16 copies
// are then read (L2/L3-resident) by all 16 m-tiles of each GEMM -- cheaper
// than fusing the convert into B-staging (r2 post-mortem: fused = 16x
// redundant VALU + 2x fetch bytes, +~100us).
// ---------------------------------------------------------------------------
__global__ __launch_bounds__(256) void cvt4(
    const float* s0, const float* s1, const float* s2, const float* s3,
    u16* d0, u16* d1, u16* d2, u16* d3,
    int n0, int n1, int n2, int n3)
{
  int r = blockIdx.y;
  const float* s = r == 0 ? s0 : r == 1 ? s1 : r == 2 ? s2 : s3;
  u16* d        = r == 0 ? d0 : r == 1 ? d1 : r == 2 ? d2 : d3;
  int n4        = r == 0 ? n0 : r == 1 ? n1 : r == 2 ? n2 : n3;
  int i = blockIdx.x * 256 + threadIdx.x;
  if (i < n4) {
    float4 v = ((const float4*)s)[i];
    ushort4 o;
    o.x = f2b(v.x); o.y = f2b(v.y); o.z = f2b(v.z); o.w = f2b(v.w);
    ((ushort4*)d)[i] = o;
  }
}

// ---------------------------------------------------------------------------
// emb_table[r][k] = byte_emb[r>>5][k] + local_pos[r&31][k], bf16 out.
// [8192, 512]: one row per (token value, local position) pair.
// ---------------------------------------------------------------------------
__global__ __launch_bounds__(256) void embed_table(
    const float* __restrict__ be, const float* __restrict__ lp, bf16* __restrict__ T)
{
  int i = blockIdx.x * 256 + threadIdx.x;   // 8192 * 64 threads, 8 elems each
  int r = i >> 6, c = (i & 63) << 3;
  int t = r >> 5, l = r & 31;
  const float* bp = be + ((long)t << 9) + c;
  const float* pp = lp + ((long)l << 9) + c;
  float4 x0 = *(const float4*)bp, x1 = *(const float4*)(bp + 4);
  float4 y0 = *(const float4*)pp, y1 = *(const float4*)(pp + 4);
  short8 o;
  o[0] = (short)f2b(x0.x + y0.x); o[1] = (short)f2b(x0.y + y0.y);
  o[2] = (short)f2b(x0.z + y0.z); o[3] = (short)f2b(x0.w + y0.w);
  o[4] = (short)f2b(x1.x + y1.x); o[5] = (short)f2b(x1.y + y1.y);
  o[6] = (short)f2b(x1.z + y1.z); o[7] = (short)f2b(x1.w + y1.w);
  *(short8*)((u16*)T + ((long)r << 9) + c) = o;
}

// ---------------------------------------------------------------------------
// C = A @ B^T (+bias)(+addf)(gelu). A bf16 [M,K], B bf16 [N,K], fp32 accum.
// 64x64 tile / 256 threads, BK=64, double-buffered LDS, one barrier per
// chunk, next chunk's global loads issued before this chunk's MFMAs.
// blockIdx.x = m-tile (fastest): weight n-tiles stay L2-resident.
// act: 0 = none, 1 = gelu, 2 = split-K partial write (bias applied only for
// bz==0; Cf = partial pool, partial z at element offset bz*sCb; no atomics --
// the following ln_kernel sums the partials).
// Split-K / batching via blockIdx.z: sAb/sBb are element offsets (K-offset
// for split-K, batch stride otherwise); sCb is the C z/batch offset.
// M % 64 == 0; N, K guarded (K tail of 32).
// ---------------------------------------------------------------------------
__global__ __launch_bounds__(256) void gemm64(
    const bf16* A, long sAb, int lda,
    const bf16* B, long sBb, int ldb,
    float* Cf, bf16* Cb, long sCb, int ldc,
    const float* bias, int biasStride,
    const float* addf,
    int M, int N, int K, int act)
{
  __shared__ u16 As[2][64][72];   // stride 144 B: 16B-aligned, 2-way-only banks
  __shared__ u16 Bs[2][64][72];
  const int bz = blockIdx.z;
  const u16* Ap = (const u16*)A + (long)bz * sAb;
  const u16* Bp = (const u16*)B + (long)bz * sBb;
  const long coff = (long)bz * sCb;
  const int m0 = blockIdx.x << 6, n0 = blockIdx.y << 6;
  const int tid = threadIdx.x;
  const int wave = tid >> 6, lane = tid & 63;
  const int sr = tid >> 3;          // staging row 0..31 (and +32)
  const int scc = (tid & 7) << 3;   // staging col 0..56
  const int br0 = n0 + sr, br1 = n0 + sr + 32;
  const short8 zz = {0,0,0,0,0,0,0,0};
  f32x4 acc[4] = {{0.f,0.f,0.f,0.f},{0.f,0.f,0.f,0.f},{0.f,0.f,0.f,0.f},{0.f,0.f,0.f,0.f}};

  // prologue: stage chunk 0 into buffer 0
  {
    int ch = K < 64 ? K : 64;
    bool kv = scc < ch;
    short8 a0 = zz, a1 = zz, b0 = zz, b1 = zz;
    if (kv) {
      a0 = *(const short8*)(Ap + (long)(m0 + sr) * lda + scc);
      a1 = *(const short8*)(Ap + (long)(m0 + sr + 32) * lda + scc);
      if (br0 < N) b0 = *(const short8*)(Bp + (long)br0 * ldb + scc);
      if (br1 < N) b1 = *(const short8*)(Bp + (long)br1 * ldb + scc);
    }
    *(short8*)&As[0][sr][scc] = a0;
    *(short8*)&As[0][sr + 32][scc] = a1;
    *(short8*)&Bs[0][sr][scc] = b0;
    *(short8*)&Bs[0][sr + 32][scc] = b1;
  }
  __syncthreads();

  const int arow = (wave << 4) + (lane & 15);
  const int kq = (lane >> 4) << 3;
  int buf = 0;
  for (int k0 = 0; k0 < K; k0 += 64) {
    int knext = k0 + 64;
    bool more = knext < K;
    short8 a0 = zz, a1 = zz, b0 = zz, b1 = zz;
    if (more) {   // issue next chunk's loads before MFMAs (overlap)
      int ch = K - knext; if (ch > 64) ch = 64;
      bool kv = scc < ch;
      if (kv) {
        a0 = *(const short8*)(Ap + (long)(m0 + sr) * lda + knext + scc);
        a1 = *(const short8*)(Ap + (long)(m0 + sr + 32) * lda + knext + scc);
        if (br0 < N) b0 = *(const short8*)(Bp + (long)br0 * ldb + knext + scc);
        if (br1 < N) b1 = *(const short8*)(Bp + (long)br1 * ldb + knext + scc);
      }
    }
    int rem = K - k0; if (rem > 64) rem = 64;
    {
      short8 af = *(const short8*)&As[buf][arow][kq];
#pragma unroll
      for (int nt = 0; nt < 4; nt++) {
        short8 bfr = *(const short8*)&Bs[buf][(nt << 4) + (lane & 15)][kq];
        acc[nt] = __builtin_amdgcn_mfma_f32_16x16x32_bf16(af, bfr, acc[nt], 0, 0, 0);
      }
    }
    if (rem > 32) {
      short8 af = *(const short8*)&As[buf][arow][32 + kq];
#pragma unroll
      for (int nt = 0; nt < 4; nt++) {
        short8 bfr = *(const short8*)&Bs[buf][(nt << 4) + (lane & 15)][32 + kq];
        acc[nt] = __builtin_amdgcn_mfma_f32_16x16x32_bf16(af, bfr, acc[nt], 0, 0, 0);
      }
    }
    if (more) {
      int nb = buf ^ 1;
      *(short8*)&As[nb][sr][scc] = a0;
      *(short8*)&As[nb][sr + 32][scc] = a1;
      *(short8*)&Bs[nb][sr][scc] = b0;
      *(short8*)&Bs[nb][sr + 32][scc] = b1;
      __syncthreads();
      buf = nb;
    }
  }

  int rbase = m0 + (wave << 4) + ((lane >> 4) << 2);
#pragma unroll
  for (int nt = 0; nt < 4; nt++) {
    int c = n0 + (nt << 4) + (lane & 15);
    if (c >= N) continue;
    float bvl = bias ? bias[bz * biasStride + c] : 0.f;
    if (act == 2 && bz != 0) bvl = 0.f;
#pragma unroll
    for (int j = 0; j < 4; j++) {
      int r = rbase + j;
      long idx = coff + (long)r * ldc + c;
      float v = acc[nt][j] + bvl;
      if (addf) v += addf[idx];
      if (act == 1) v = 0.5f * v * (1.f + erff(v * 0.70710678118654752f));
      if (Cf) Cf[idx] = v;
      if (Cb) Cb[idx] = __float2bfloat16(v);
    }
  }
}

// ---------------------------------------------------------------------------
// Fused flash-style MHA, key-split for occupancy (r4 post-mortem: 256 blocks
// x 2 waves = 0.5 wave/SIMD, latency-starved at 42us). Grid (32 q-tiles,
// 8 heads, KSPLIT=4): each block streams 256 keys (8 tiles) and emits an
// UNNORMALIZED fp32 partial O plus per-q-row (m, l); attn_combine merges.
// Swapped QK^T: mfma(K_frag, Q_frag) -> lane holds 8 scores of ONE q-row;
// row max/sum are 2x shfl_xor. Online softmax with exact-skip rescale.
// P repack to PV A-frag via 8 __shfl. PV B operand from Vt[d][k] directly.
// ---------------------------------------------------------------------------
__global__ __launch_bounds__(128) void fused_attn(
    const bf16* __restrict__ qkvt,  // [1024,2304]  Q|K|V
    const bf16* __restrict__ Vt,    // [768,1024]   V transposed (d-major)
    float* __restrict__ Op,         // [4][8][1024][96] unnormalized partial O
    float* __restrict__ marr,       // [4][8][1024] running max
    float* __restrict__ larr)       // [4][8][1024] running sum
{
  const int h = blockIdx.y;
  const int ks = blockIdx.z;
  const int wid = threadIdx.x >> 6;
  const int lane = threadIdx.x & 63;
  const int q0 = (blockIdx.x << 5) + (wid << 4);
  const int lr = lane & 15;
  const int lq = lane >> 4;
  const int kbase = ks << 8;
  const float scale = 0.10206207261596577f;  // 96^-0.5

  const u16* qp = (const u16*)qkvt;
  const u16* kp = qp + 768 + h * 96 + (lq << 3);
  const u16* vp = (const u16*)Vt + ((long)(h * 96 + lr) << 10) + (lq << 3);

  // Q fragments (B operand of swapped QK): Q[q0+lr][h*96 + c*32 + lq*8 ..+7]
  short8 qf[3];
#pragma unroll
  for (int c = 0; c < 3; c++)
    qf[c] = *(const short8*)(qp + (long)(q0 + lr) * 2304 + h * 96 + (c << 5) + (lq << 3));

  f32x4 o[6] = {{0.f,0.f,0.f,0.f},{0.f,0.f,0.f,0.f},{0.f,0.f,0.f,0.f},
                {0.f,0.f,0.f,0.f},{0.f,0.f,0.f,0.f},{0.f,0.f,0.f,0.f}};
  float m = -INFINITY, l = 0.f;

  for (int k0 = kbase; k0 < kbase + 256; k0 += 32) {
    f32x4 s0 = {0.f,0.f,0.f,0.f}, s1 = {0.f,0.f,0.f,0.f};
#pragma unroll
    for (int c = 0; c < 3; c++) {
      short8 kf0 = *(const short8*)(kp + (long)(k0 + lr) * 2304 + (c << 5));
      short8 kf1 = *(const short8*)(kp + (long)(k0 + 16 + lr) * 2304 + (c << 5));
      s0 = __builtin_amdgcn_mfma_f32_16x16x32_bf16(kf0, qf[c], s0, 0, 0, 0);
      s1 = __builtin_amdgcn_mfma_f32_16x16x32_bf16(kf1, qf[c], s1, 0, 0, 0);
    }
    // lane holds scores of q-row lr at keys k0+lq*4+r (s0) and k0+16+lq*4+r (s1)
    float e0[4], e1[4];
    float mx = -INFINITY;
#pragma unroll
    for (int r = 0; r < 4; r++) {
      e0[r] = s0[r] * scale;
      e1[r] = s1[r] * scale;
      mx = fmaxf(mx, fmaxf(e0[r], e1[r]));
    }
    mx = fmaxf(mx, __shfl_xor(mx, 16));
    mx = fmaxf(mx, __shfl_xor(mx, 32));
    float mn = fmaxf(m, mx);
    float ts = 0.f;
#pragma unroll
    for (int r = 0; r < 4; r++) {
      e0[r] = __expf(e0[r] - mn);
      e1[r] = __expf(e1[r] - mn);
      ts += e0[r] + e1[r];
    }
    ts += __shfl_xor(ts, 16);
    ts += __shfl_xor(ts, 32);
    if (!__all(mx <= m)) {   // some q-row's max grew: rescale O (exact skip else)
      float f = __expf(m - mn);
      float fr[4];
#pragma unroll
      for (int r = 0; r < 4; r++) fr[r] = __shfl(f, (lq << 2) + r);
#pragma unroll
      for (int n = 0; n < 6; n++)
#pragma unroll
        for (int r = 0; r < 4; r++) o[n][r] *= fr[r];
      l *= f;
    }
    l += ts;
    m = mn;

    // pack P to bf16 pairs, then cross-lane repack: PV A-frag lane (lq,lr)
    // needs keys 8*lq..8*lq+7 of q-row lr; sources are quadrant pair
    // (2*(lq&1), 2*(lq&1)+1), kt = lq>>1.
    unsigned a01 = ((unsigned)f2b(e0[1]) << 16) | f2b(e0[0]);
    unsigned a23 = ((unsigned)f2b(e0[3]) << 16) | f2b(e0[2]);
    unsigned b01 = ((unsigned)f2b(e1[1]) << 16) | f2b(e1[0]);
    unsigned b23 = ((unsigned)f2b(e1[3]) << 16) | f2b(e1[2]);
    int sA = lr + ((lq & 1) << 5);   // lane with lower 4 target keys
    int sB = sA + 16;                // lane with upper 4 target keys
    unsigned qa01 = (unsigned)__shfl((int)a01, sA);
    unsigned qa23 = (unsigned)__shfl((int)a23, sA);
    unsigned qb01 = (unsigned)__shfl((int)b01, sA);
    unsigned qb23 = (unsigned)__shfl((int)b23, sA);
    unsigned ra01 = (unsigned)__shfl((int)a01, sB);
    unsigned ra23 = (unsigned)__shfl((int)a23, sB);
    unsigned rb01 = (unsigned)__shfl((int)b01, sB);
    unsigned rb23 = (unsigned)__shfl((int)b23, sB);
    bool hi = lq >= 2;               // kt1 keys for quadrants 2,3
    u32x4 wv;
    wv[0] = hi ? qb01 : qa01;
    wv[1] = hi ? qb23 : qa23;
    wv[2] = hi ? rb01 : ra01;
    wv[3] = hi ? rb23 : ra23;
    short8 pa = __builtin_bit_cast(short8, wv);

#pragma unroll
    for (int n = 0; n < 6; n++) {
      short8 vf = *(const short8*)(vp + (long)(n << 4) * 1024 + k0);
      o[n] = __builtin_amdgcn_mfma_f32_16x16x32_bf16(pa, vf, o[n], 0, 0, 0);
    }
  }

  // emit unnormalized partial: O rows q0+lq*4+r, cols n*16+lr
  float* Opf = Op + (long)(ks * 8 + h) * 98304;
#pragma unroll
  for (int r = 0; r < 4; r++)
#pragma unroll
    for (int n = 0; n < 6; n++)
      Opf[(long)(q0 + (lq << 2) + r) * 96 + (n << 4) + lr] = o[n][r];
  if (lq == 0) {   // every lane holds (m,l) of its q-row lr
    int idx = (ks * 8 + h) * 1024 + q0 + lr;
    marr[idx] = m;
    larr[idx] = l;
  }
}

// ---------------------------------------------------------------------------
// Merge the 4 key-split partials: M = max m_ks, w = exp(m_ks - M),
// attn[q][h*96+d] = (sum_ks Op*w) / (sum_ks l*w). Block = (q, h), 128 thr.
// ---------------------------------------------------------------------------
__global__ __launch_bounds__(128) void attn_combine(
    const float* __restrict__ Op, const float* __restrict__ marr,
    const float* __restrict__ larr, bf16* __restrict__ attn)
{
  int q = blockIdx.x, h = blockIdx.y;
  int t = threadIdx.x;
  int base = h * 1024 + q;            // per-split stride 8192
  float m0 = marr[base], m1 = marr[8192 + base];
  float m2 = marr[16384 + base], m3 = marr[24576 + base];
  float M = fmaxf(fmaxf(m0, m1), fmaxf(m2, m3));
  float w0 = __expf(m0 - M), w1 = __expf(m1 - M);
  float w2 = __expf(m2 - M), w3 = __expf(m3 - M);
  float L = larr[base] * w0 + larr[8192 + base] * w1
          + larr[16384 + base] * w2 + larr[24576 + base] * w3;
  if (t < 96) {
    long o = (long)base * 96 + t;     // per-split stride 786432
    float v = Op[o] * w0 + Op[786432 + o] * w1
            + Op[1572864 + o] * w2 + Op[2359296 + o] * w3;
    ((u16*)attn)[(long)q * 768 + h * 96 + t] = f2b(v / L);
  }
}

// ---------------------------------------------------------------------------
// Per-patch MHA over 32 bytes (4 heads, d=128) fused with masked mean.
// Q/K come from the per-(token,pos) table qkt [8192,1024]: row for byte j of
// patch p is (tokens[p*32+j]<<5)|j. MFMA QK^T (no LDS, no spills): wave =
// head; 2x2 16x16 C-tiles, 4 k-chunks.
// ---------------------------------------------------------------------------
__global__ __launch_bounds__(256) void patch_attn(
    const bf16* __restrict__ qkt,  // [8192, 1024] = [Q|K] per (token,pos)
    const int* __restrict__ tokens, const int* __restrict__ lengths,
    const float* __restrict__ byte_emb, const float* __restrict__ local_pos,
    bf16* __restrict__ Z)          // [1024, 4, 512]
{
  __shared__ float wsum[4][32];
  __shared__ int tok_s[32];
  __shared__ int cnt_s;
  int p = blockIdx.x;
  int tid = threadIdx.x;
  if (tid < 32) tok_s[tid] = tokens[p * 32 + tid];
  if (tid == 0) cnt_s = lengths[p];
  __syncthreads();
  int cnt = cnt_s;
  int h = tid >> 6, lane = tid & 63;
  const int rsel = lane & 15;
  const int ksel = (lane >> 4) << 3;
  const u16* qkb = (const u16*)qkt + h * 128;
  const long r0 = ((long)((tok_s[rsel] << 5) | rsel)) << 10;
  const long r1 = ((long)((tok_s[16 + rsel] << 5) | (16 + rsel))) << 10;

  f32x4 acc[2][2] = {{{0.f,0.f,0.f,0.f},{0.f,0.f,0.f,0.f}},
                     {{0.f,0.f,0.f,0.f},{0.f,0.f,0.f,0.f}}};
#pragma unroll
  for (int kc = 0; kc < 4; kc++) {
    int ko = kc * 32 + ksel;
    short8 a0 = *(const short8*)(qkb + r0 + ko);
    short8 a1 = *(const short8*)(qkb + r1 + ko);
    short8 b0 = *(const short8*)(qkb + r0 + 512 + ko);
    short8 b1 = *(const short8*)(qkb + r1 + 512 + ko);
    acc[0][0] = __builtin_amdgcn_mfma_f32_16x16x32_bf16(a0, b0, acc[0][0], 0, 0, 0);
    acc[0][1] = __builtin_amdgcn_mfma_f32_16x16x32_bf16(a0, b1, acc[0][1], 0, 0, 0);
    acc[1][0] = __builtin_amdgcn_mfma_f32_16x16x32_bf16(a1, b0, acc[1][0], 0, 0, 0);
    acc[1][1] = __builtin_amdgcn_mfma_f32_16x16x32_bf16(a1, b1, acc[1][1], 0, 0, 0);
  }

  const float scale = 0.088388347648318447f;  // 128^-0.5
  int j0 = lane & 15, j1 = 16 + j0;
  bool v0 = j0 < cnt, v1 = j1 < cnt;
  int rowq = (lane >> 4) << 2;
  float cs0 = 0.f, cs1 = 0.f;   // column-sum partials for cols j0, j1
#pragma unroll
  for (int ti = 0; ti < 2; ti++) {
    float s0[4], s1[4], mx[4], sm[4], e0[4], e1[4];
#pragma unroll
    for (int r = 0; r < 4; r++) {
      s0[r] = acc[ti][0][r] * scale;
      s1[r] = acc[ti][1][r] * scale;
      float a = v0 ? s0[r] : -1e30f;
      float b = v1 ? s1[r] : -1e30f;
      mx[r] = fmaxf(a, b);
    }
#pragma unroll
    for (int d = 1; d < 16; d <<= 1)
#pragma unroll
      for (int r = 0; r < 4; r++) mx[r] = fmaxf(mx[r], __shfl_xor(mx[r], d));
#pragma unroll
    for (int r = 0; r < 4; r++) {
      e0[r] = v0 ? __expf(s0[r] - mx[r]) : 0.f;
      e1[r] = v1 ? __expf(s1[r] - mx[r]) : 0.f;
      sm[r] = e0[r] + e1[r];
    }
#pragma unroll
    for (int d = 1; d < 16; d <<= 1)
#pragma unroll
      for (int r = 0; r < 4; r++) sm[r] += __shfl_xor(sm[r], d);
#pragma unroll
    for (int r = 0; r < 4; r++) {
      int row = ti * 16 + rowq + r;
      if (row < cnt) {
        float inv = 1.f / sm[r];
        cs0 += e0[r] * inv;
        cs1 += e1[r] * inv;
      }
    }
  }
  cs0 += __shfl_xor(cs0, 16); cs0 += __shfl_xor(cs0, 32);
  cs1 += __shfl_xor(cs1, 16); cs1 += __shfl_xor(cs1, 32);
  if (lane < 16) {
    float invc = 1.f / (float)cnt;
    wsum[h][lane] = cs0 * invc;
    wsum[h][16 + lane] = cs1 * invc;
  }
  __syncthreads();

  // z_h[e] = sum_j wsum[h][j] * emb[j][e]
  for (int e = tid; e < 512; e += 256) {
    float za0 = 0.f, za1 = 0.f, za2 = 0.f, za3 = 0.f;
    for (int j = 0; j < cnt; j++) {
      float ev = byte_emb[((long)tok_s[j] << 9) + e] + local_pos[((long)j << 9) + e];
      za0 += wsum[0][j] * ev;
      za1 += wsum[1][j] * ev;
      za2 += wsum[2][j] * ev;
      za3 += wsum[3][j] * ev;
    }
    long zb = (long)p * 2048;
    Z[zb + e]        = __float2bfloat16(za0);
    Z[zb + 512 + e]  = __float2bfloat16(za1);
    Z[zb + 1024 + e] = __float2bfloat16(za2);
    Z[zb + 1536 + e] = __float2bfloat16(za3);
  }
}

// ---------------------------------------------------------------------------
// Row LayerNorm over 768 cols, with optional fused residual-partial sum:
// v = x[row] + a0 + a1 + a2 + a3 (each nullable); if hout, hout[row] = v
// (persist updated residual); then LN(v)*w+b -> outb (bf16) / outf (fp32).
// ---------------------------------------------------------------------------
__global__ __launch_bounds__(256) void ln_kernel(
    const float* __restrict__ x,
    const float* __restrict__ a0, const float* __restrict__ a1,
    const float* __restrict__ a2, const float* __restrict__ a3,
    float* __restrict__ hout,
    const float* __restrict__ w, const float* __restrict__ b,
    bf16* outb, float* outf)
{
  __shared__ float red[8];
  __shared__ float mv[2];
  int row = blockIdx.x;
  long base = (long)row * DD;
  int tid = threadIdx.x, lane = tid & 63, wave = tid >> 6;
  float vv[3];
  float s = 0.f, s2 = 0.f;
#pragma unroll
  for (int j = 0; j < 3; j++) {
    long c = base + tid + j * 256;
    float v = x[c];
    if (a0) v += a0[c];
    if (a1) v += a1[c];
    if (a2) v += a2[c];
    if (a3) v += a3[c];
    if (hout) hout[c] = v;
    vv[j] = v; s += v; s2 += v * v;
  }
  for (int o = 32; o; o >>= 1) { s += __shfl_down(s, o); s2 += __shfl_down(s2, o); }
  if (lane == 0) { red[wave] = s; red[4 + wave] = s2; }
  __syncthreads();
  if (tid == 0) {
    float ts = red[0] + red[1] + red[2] + red[3];
    float ts2 = red[4] + red[5] + red[6] + red[7];
    float mu = ts / DD;
    float var = ts2 / DD - mu * mu;
    mv[0] = mu; mv[1] = rsqrtf(var + 1e-5f);
  }
  __syncthreads();
  float mu = mv[0], rstd = mv[1];
#pragma unroll
  for (int j = 0; j < 3; j++) {
    int c = tid + j * 256;
    float v = (vv[j] - mu) * rstd * w[c] + b[c];
    if (outb) outb[base + c] = __float2bfloat16(v);
    if (outf) outf[base + c] = v;
  }
}

// ---------------------------------------------------------------------------
// Vt[d][k] = qkv[k][1536 + d]  (V part), 32x32 LDS tiles. bf16.
// ---------------------------------------------------------------------------
__global__ __launch_bounds__(256) void transpose_v(
    const bf16* __restrict__ qkv, bf16* __restrict__ Vt)
{
  __shared__ u16 tile[32][33];
  int k0 = blockIdx.x << 5;
  int d0 = blockIdx.y << 5;
  int tx = threadIdx.x & 31, ty = threadIdx.x >> 5;
  const u16* q = (const u16*)qkv;
  for (int i = ty; i < 32; i += 8)
    tile[i][tx] = q[(long)(k0 + i) * 2304 + 1536 + d0 + tx];
  __syncthreads();
  u16* vt = (u16*)Vt;
  for (int i = ty; i < 32; i += 8)
    vt[(long)(d0 + i) * 1024 + k0 + tx] = tile[tx][i];
}

extern "C" void kernel_launch(void* const* d_in, const int* in_sizes, int n_in,
                              void* d_out, int out_size, void* d_ws, size_t ws_size,
                              hipStream_t stream)
{
  const int*   tokens    = (const int*)d_in[0];
  const int*   lengths   = (const int*)d_in[1];
  const float* byte_emb  = (const float*)d_in[2];
  const float* local_pos = (const float*)d_in[3];
  const float* patch_pos = (const float*)d_in[4];
  const float* pa_qkv_w  = (const float*)d_in[5];
  const float* pa_qkv_b  = (const float*)d_in[6];
  const float* pa_out_w  = (const float*)d_in[7];
  const float* pa_out_b  = (const float*)d_in[8];
  const float* proj_w    = (const float*)d_in[9];
  const float* proj_b    = (const float*)d_in[10];
  const float* Wqkv      = (const float*)d_in[11];
  const float* Bqkv      = (const float*)d_in[12];
  const float* Wout      = (const float*)d_in[13];
  const float* Bout      = (const float*)d_in[14];
  const float* ln1w      = (const float*)d_in[15];
  const float* ln1b      = (const float*)d_in[16];
  const float* ln2w      = (const float*)d_in[17];
  const float* ln2b      = (const float*)d_in[18];
  const float* W1        = (const float*)d_in[19];
  const float* B1        = (const float*)d_in[20];
  const float* W2        = (const float*)d_in[21];
  const float* B2        = (const float*)d_in[22];
  const float* lnfw      = (const float*)d_in[23];
  const float* lnfb      = (const float*)d_in[24];

  char* ws = (char*)d_ws;
  const size_t MB = 1ull << 20;
  // ---- layout (<= 73 MB; proven budget >= 82 MB) ----
  bf16* qkT    = (bf16*)(ws);              // [0,16)  phase1 QK table [8192,1024]
  bf16* qkvt   = (bf16*)(ws + 16 * MB);    // [16,21) [1024,2304]
  bf16* Vt     = (bf16*)(ws + 21 * MB);    // [21,23) [768,1024]
  bf16* attn   = (bf16*)(ws + 23 * MB);    // [23,25) [1024,768]
  bf16* ffb    = (bf16*)(ws + 25 * MB);    // [25,31) [1024,3072]
  float* h     = (float*)(ws + 31 * MB);   // [31,34) [1024,768] fp32
  bf16* hn     = (bf16*)(ws + 34 * MB);    // [34,36)
  u16*  Lw     = (u16*)(ws + 36 * MB);     // [36,50) per-layer bf16 weights
  bf16* embT   = (bf16*)(ws + 50 * MB);    // [50,58) phase1 emb table [8192,512]
  float* hp    = (float*)(ws + 58 * MB);   // [58,70) split-K partials 4x[1024,768] fp32;
                                           //         also attn partial O 4x[8,1024,96] (12 MB,
                                           //         written by fused_attn, read by combine
                                           //         BEFORE out-proj overwrites slots 0..1)
  bf16* Z      = (bf16*)(ws + 64 * MB);    // [64,68) [1024,4,512] (phase1 only; overlaps hp)
  bf16* o_mean = (bf16*)(ws + 68 * MB);    // [68,69) (phase1)
  bf16* t1     = (bf16*)(ws + 69 * MB);    // [69,70) (phase1)
  u16*  P1w    = (u16*)(ws + 70 * MB);     // [70,73) phase1 bf16 weights (phase-2: ml arrays)
  float* marr  = (float*)(ws + 70 * MB);            // [4][8][1024] fp32 (128 KB)
  float* larr  = (float*)(ws + 70 * MB + 131072);   // [4][8][1024] fp32 (128 KB)

  const long PSTRIDE = (long)PP * DD;      // partial slot stride (elements)

  // per-layer pool offsets (u16 elements)
  const long oLQKV = 0;          // [2304,768]
  const long oLOUT = 1769472;    // [768,768]
  const long oLW1  = 2359296;    // [3072,768]
  const long oLW2  = 4718592;    // [768,3072]
  // phase-1 pool offsets
  const long oPAQ  = 0;          // [1536,512]
  const long oPAO  = 786432;     // [512,512]
  const long oPRJ  = 1048576;    // [768,512]

  // ---- phase 1 ----
  cvt4<<<dim3(768, 3), 256, 0, stream>>>(
      pa_qkv_w, pa_out_w, proj_w, nullptr,
      P1w + oPAQ, P1w + oPAO, P1w + oPRJ, nullptr,
      786432 / 4, 262144 / 4, 393216 / 4, 0);
  // embT[(t<<5)|l] = byte_emb[t] + local_pos[l]  (bf16, all 8192 combos)
  embed_table<<<2048, 256, 0, stream>>>(byte_emb, local_pos, embT);
  // qkT = embT @ Wqk^T + bqk   [8192,1024]: 4x fewer FLOPs than per-byte Q/K
  gemm64<<<dim3(128, 16, 1), 256, 0, stream>>>(
      embT, 0, EE, (bf16*)(P1w + oPAQ), 0, EE, nullptr, qkT, 0, 1024,
      pa_qkv_b, 0, nullptr, 8192, 1024, EE, 0);
  patch_attn<<<PP, 256, 0, stream>>>(
      qkT, tokens, lengths, byte_emb, local_pos, Z);
  // o_mean[:, h*128:(h+1)*128] = Z[:,h,:] @ Wv_h^T + bv_h
  gemm64<<<dim3(16, 2, 4), 256, 0, stream>>>(
      Z, 512, 2048, (bf16*)(P1w + oPAQ + 1024L * EE), 128L * EE, EE,
      nullptr, o_mean, 128, EE, pa_qkv_b + 1024, 128, nullptr, PP, 128, EE, 0);
  // t1 = o_mean @ pa_out_w^T + b
  gemm64<<<dim3(16, 8, 1), 256, 0, stream>>>(
      o_mean, 0, EE, (bf16*)(P1w + oPAO), 0, EE, nullptr, t1, 0, EE,
      pa_out_b, 0, nullptr, PP, EE, EE, 0);
  // h = t1 @ proj_w^T + b + patch_pos (fp32)
  gemm64<<<dim3(16, 12, 1), 256, 0, stream>>>(
      t1, 0, EE, (bf16*)(P1w + oPRJ), 0, EE, h, nullptr, 0, DD,
      proj_b, 0, patch_pos, PP, DD, EE, 0);

  // ---- phase 2: transformer encoder ----
  for (int i = 0; i < NLAYER; i++) {
    cvt4<<<dim3(2304, 4), 256, 0, stream>>>(
        Wqkv + (long)i * 2304 * DD, Wout + (long)i * DD * DD,
        W1 + (long)i * FFDIM * DD, W2 + (long)i * DD * FFDIM,
        Lw + oLQKV, Lw + oLOUT, Lw + oLW1, Lw + oLW2,
        1769472 / 4, 589824 / 4, 2359296 / 4, 2359296 / 4);
    // ln1: for i>0 also folds in previous layer's ff2 partials and updates h
    if (i == 0)
      ln_kernel<<<PP, 256, 0, stream>>>(h, nullptr, nullptr, nullptr, nullptr,
                                        nullptr, ln1w + i * DD, ln1b + i * DD, hn, nullptr);
    else
      ln_kernel<<<PP, 256, 0, stream>>>(h, hp, hp + PSTRIDE, hp + 2 * PSTRIDE, hp + 3 * PSTRIDE,
                                        h, ln1w + i * DD, ln1b + i * DD, hn, nullptr);
    gemm64<<<dim3(16, 36, 1), 256, 0, stream>>>(
        hn, 0, DD, (bf16*)(Lw + oLQKV), 0, DD, nullptr, qkvt, 0, 2304,
        Bqkv + i * 2304, 0, nullptr, PP, 2304, DD, 0);
    transpose_v<<<dim3(32, 24), 256, 0, stream>>>(qkvt, Vt);
    // fused QK^T + softmax + PV, 4-way key-split (occupancy), then combine
    fused_attn<<<dim3(32, 8, 4), 128, 0, stream>>>(qkvt, Vt, hp, marr, larr);
    attn_combine<<<dim3(1024, 8), 128, 0, stream>>>(hp, marr, larr, attn);
    // out-proj split-K 2x -> partials hp[0..1] (no atomics; summed in ln2)
    gemm64<<<dim3(16, 12, 2), 256, 0, stream>>>(
        attn, 384, DD, (bf16*)(Lw + oLOUT), 384, DD, hp, nullptr, PSTRIDE, DD,
        Bout + i * DD, 0, nullptr, PP, DD, 384, 2);
    // ln2: h += p0 + p1, then LN -> hn
    ln_kernel<<<PP, 256, 0, stream>>>(h, hp, hp + PSTRIDE, nullptr, nullptr,
                                      h, ln2w + i * DD, ln2b + i * DD, hn, nullptr);
    // ffb = gelu(hn @ W1^T + b1)
    gemm64<<<dim3(16, 48, 1), 256, 0, stream>>>(
        hn, 0, DD, (bf16*)(Lw + oLW1), 0, DD, nullptr, ffb, 0, FFDIM,
        B1 + i * FFDIM, 0, nullptr, PP, FFDIM, DD, 1);
    // ff2 split-K 4x -> partials hp[0..3] (summed in next ln1 / final ln)
    gemm64<<<dim3(16, 12, 4), 256, 0, stream>>>(
        ffb, 768, FFDIM, (bf16*)(Lw + oLW2), 768, FFDIM, hp, nullptr, PSTRIDE, DD,
        B2 + i * DD, 0, nullptr, PP, DD, 768, 2);
  }
  // final LN folds in layer-5 ff2 partials
  ln_kernel<<<PP, 256, 0, stream>>>(h, hp, hp + PSTRIDE, hp + 2 * PSTRIDE, hp + 3 * PSTRIDE,
                                    nullptr, lnfw, lnfb, nullptr, (float*)d_out);
}